// Round 12
// baseline (151.748 us; speedup 1.0000x reference)
//
#include <hip/hip_runtime.h>
#include <hip/hip_bf16.h>

#define BB 32
#define CC 192
#define HH 64
#define WW 64
#define OO 192
#define EE 8
#define KTOT (CC*9)      // 1728
#define NSP (HH*WW)      // 4096
#define EWN (OO*CC*9)    // 331776 per expert

typedef __attribute__((ext_vector_type(8))) __bf16 bf16x8;
typedef __attribute__((ext_vector_type(4))) float f32x4;

// async global->LDS, 16B per lane (dest = wave-uniform base + lane*16)
__device__ __forceinline__ void gl_lds16(const void* g, void* l) {
    __builtin_amdgcn_global_load_lds(
        (const __attribute__((address_space(1))) unsigned int*)g,
        (__attribute__((address_space(3))) unsigned int*)l, 16, 0, 0);
}

// ---------------- kernel 1: fused transpose (NCHW f32 -> NHWC bf16) + global avg pool ----
__global__ __launch_bounds__(256) void transpose_pool_kernel(const float* __restrict__ x,
                                                             __bf16* __restrict__ xT,
                                                             float* __restrict__ pooled) {
    const int h = blockIdx.x, b = blockIdx.y;
    __shared__ float T[CC][65];   // 49920 B
    const int t = threadIdx.x;
    const float* xb = x + (size_t)b * CC * NSP + h * WW;
#pragma unroll
    for (int i = 0; i < 12; ++i) {
        const int g = i * 256 + t;          // 0..3071
        const int c = g >> 4;
        const int w4 = (g & 15) * 4;
        float4 v = *(const float4*)(xb + (size_t)c * NSP + w4);
        T[c][w4 + 0] = v.x; T[c][w4 + 1] = v.y;
        T[c][w4 + 2] = v.z; T[c][w4 + 3] = v.w;
    }
    __syncthreads();
    if (t < CC) {
        float s = 0.f;
#pragma unroll 8
        for (int w = 0; w < WW; ++w) s += T[t][w];
        atomicAdd(pooled + b * CC + t, s);
    }
#pragma unroll
    for (int i = 0; i < 6; ++i) {
        const int ch = i * 256 + t;         // 0..1535
        const int w = ch / 24;
        const int cg = ch - w * 24;
        bf16x8 o;
#pragma unroll
        for (int j = 0; j < 8; ++j) o[j] = (__bf16)T[cg * 8 + j][w];
        *(bf16x8*)(xT + (((size_t)b * HH + h) * WW + w) * CC + cg * 8) = o;
    }
}

// ---------------- kernel 2: mix expert weights -> bf16 (LDS-staged, coalesced reads) ----
__global__ __launch_bounds__(256) void mix_kernel(const float* __restrict__ ew,
                                                  const float* __restrict__ pooled,
                                                  const float* __restrict__ rw,
                                                  const float* __restrict__ rb,
                                                  __bf16* __restrict__ wmT) {
    __shared__ float r[4 * EE];
    __shared__ float es[EE * KTOT];   // 55296 B
    const int t = threadIdx.x;
    const int o = blockIdx.x;
    const int b0 = blockIdx.y * 4;
    const size_t base = (size_t)o * KTOT;
    for (int u = t; u < EE * (KTOT / 4); u += 256) {
        const int e = u / (KTOT / 4);
        const int s4 = u - e * (KTOT / 4);
        *(float4*)&es[e * KTOT + s4 * 4] =
            *(const float4*)(ew + (size_t)e * EWN + base + s4 * 4);
    }
    {
        const int p = t >> 3, q = t & 7;
        if (p < 32) {
            const int bl = p >> 3, e = p & 7;
            const float* pb = pooled + (b0 + bl) * CC + q * 24;
            const float* we = rw + e * CC + q * 24;
            float s = 0.f;
#pragma unroll
            for (int c = 0; c < 24; ++c) s += pb[c] * we[c];
            s += __shfl_xor(s, 4);
            s += __shfl_xor(s, 2);
            s += __shfl_xor(s, 1);
            if (q == 0) {
                s = s * (1.0f / 4096.0f) + rb[e];
                r[bl * EE + e] = 1.0f / (1.0f + expf(-s));
            }
        }
    }
    __syncthreads();
    for (int i = 0; i < 7; ++i) {
        const int jl = t + 256 * i;
        if (jl >= KTOT) break;
        const int c = jl % 192;
        const int t9 = jl / 192;
        const int s = c * 9 + t9;
        float w8[EE];
#pragma unroll
        for (int e = 0; e < EE; ++e) w8[e] = es[e * KTOT + s];
#pragma unroll
        for (int bi = 0; bi < 4; ++bi) {
            float acc = 0.f;
#pragma unroll
            for (int e = 0; e < EE; ++e) acc += r[bi * EE + e] * w8[e];
            wmT[(size_t)(b0 + bi) * EWN + base + jl] = (__bf16)acc;
        }
    }
}

// ---------------- kernel 3: NHWC implicit-GEMM conv, 4-phase 1-block/CU template ----
// BM=192 x BN=256 (4 h-rows), BK=64, 512 thr (8 waves 2Mx4N; per-wave 96x64).
// LDS 2 x 56KB = 112KB -> 1 block/CU. Per K-step, 4 phases:
//   {stage-part(next) | [P0: vmcnt(2)+bar] ds_read subtile | bar | 12 MFMA | bar}
// Counted vmcnt once per step; next-step loads stay in flight across all phases.
#define A_ELEMS (192*64)   // 12288 elems = 24 KB
#define B_ELEMS (256*64)   // 16384 elems = 32 KB
#define BUFE (A_ELEMS + B_ELEMS)   // 28672 elems = 57344 B

__global__ __launch_bounds__(512) void conv_kernel(const __bf16* __restrict__ xT,
                                                   const __bf16* __restrict__ wmT,
                                                   const __bf16* __restrict__ zp,
                                                   float* __restrict__ out) {
    extern __shared__ __bf16 smem[];   // 2 * BUFE = 114688 B

    // bijective XCD swizzle: 512 blocks; each XCD gets 4 consecutive b x 16 h-groups
    const int gid = blockIdx.x;              // 0..511
    const int nid = (gid & 7) * 64 + (gid >> 3);
    const int b  = nid >> 4;                 // 0..31
    const int h0 = (nid & 15) * 4;           // 0,4,..,60

    const int t = threadIdx.x;
    const int lane = t & 63;
    const int wv = t >> 6;                   // 0..7
    const int wr  = wv >> 2;                 // 0..1 (M half: 96 rows)
    const int wcN = wv & 3;                  // 0..3 (N quarter: one h-row)
    const int l15 = lane & 15, lch = lane >> 4;
    const int lrow = lane >> 3;              // 0..7
    const int offB = (((lane & 7) ^ lrow) << 4);   // pre-swizzled source byte offset

    const char* wmb = (const char*)(wmT + (size_t)b * (OO * KTOT));
    const char* xtb = (const char*)(xT + (size_t)b * (HH * WW * CC));
    const char* zpb = (const char*)zp;

    f32x4 acc[6][4];
#pragma unroll
    for (int mi = 0; mi < 6; ++mi)
#pragma unroll
        for (int ni = 0; ni < 4; ++ni) acc[mi][ni] = (f32x4){0.f, 0.f, 0.f, 0.f};

    auto STAGE_A1 = [&](int buf, int step, int i) {
        __bf16* As = smem + buf * BUFE;
        const int chunk = wv * 3 + i;
        const char* src = wmb + (size_t)(chunk * 8 + lrow) * (KTOT * 2)
                          + (size_t)step * 128 + offB;
        gl_lds16(src, (void*)(As + chunk * 512));
    };
    auto STAGE_B1 = [&](int buf, int step, int i) {
        const int t9 = step / 3;
        const int cc = step - t9 * 3;
        const int kh = t9 / 3;
        const int kw = t9 - kh * 3;
        __bf16* Bs = smem + buf * BUFE + A_ELEMS;
        const int chunk = wv * 4 + i;
        const int n = chunk * 8 + lrow;          // 0..255
        const int hl = n >> 6;
        const int w = n & 63;
        const int hp = h0 + hl + kh - 1;
        const int wp = w + kw - 1;
        const bool ok = ((unsigned)hp < (unsigned)HH) && ((unsigned)wp < (unsigned)WW);
        const char* src = ok
            ? xtb + ((size_t)(hp * WW + wp) * CC + cc * 64) * 2 + offB
            : zpb + offB;
        gl_lds16(src, (void*)(Bs + chunk * 512));
    };

    // prologue: step 0's 7 loads
#pragma unroll
    for (int i = 0; i < 3; ++i) STAGE_A1(0, 0, i);
#pragma unroll
    for (int i = 0; i < 4; ++i) STAGE_B1(0, 0, i);

    for (int step = 0; step < 27; ++step) {
        const int cur = step & 1;
        const int nb = cur ^ 1;
        const bool pf = (step < 26);
        const char* As = (const char*)(smem + cur * BUFE);
        const char* Bs = As + A_ELEMS * 2;
        bf16x8 a[3], bbf[4];

        // ================= phase 0 : kc0, mi 0..2 (+ B frags kc0) =================
        if (pf) {
            STAGE_A1(nb, step + 1, 0);
            STAGE_A1(nb, step + 1, 1);
            asm volatile("s_waitcnt vmcnt(2)" ::: "memory");   // cur's 7 landed
        } else {
            asm volatile("s_waitcnt vmcnt(0)" ::: "memory");
        }
        __builtin_amdgcn_s_barrier();            // all waves' loads landed
        __builtin_amdgcn_sched_barrier(0);
#pragma unroll
        for (int ni = 0; ni < 4; ++ni) {
            const int r = wcN * 64 + ni * 16 + l15;
            bbf[ni] = *(const bf16x8*)(Bs + r * 128 + ((lch * 16) ^ ((r & 7) << 4)));
        }
#pragma unroll
        for (int i = 0; i < 3; ++i) {
            const int r = wr * 96 + i * 16 + l15;
            a[i] = *(const bf16x8*)(As + r * 128 + ((lch * 16) ^ ((r & 7) << 4)));
        }
        __builtin_amdgcn_sched_barrier(0);
        __builtin_amdgcn_s_setprio(1);
#pragma unroll
        for (int i = 0; i < 3; ++i)
#pragma unroll
            for (int ni = 0; ni < 4; ++ni)
                acc[i][ni] = __builtin_amdgcn_mfma_f32_16x16x32_bf16(
                    a[i], bbf[ni], acc[i][ni], 0, 0, 0);
        __builtin_amdgcn_s_setprio(0);
        __builtin_amdgcn_s_barrier();
        __builtin_amdgcn_sched_barrier(0);

        // ================= phase 1 : kc0, mi 3..5 =================
#pragma unroll
        for (int i = 0; i < 3; ++i) {
            const int r = wr * 96 + (3 + i) * 16 + l15;
            a[i] = *(const bf16x8*)(As + r * 128 + ((lch * 16) ^ ((r & 7) << 4)));
        }
        if (pf) { STAGE_A1(nb, step + 1, 2); STAGE_B1(nb, step + 1, 0); }
        __builtin_amdgcn_sched_barrier(0);
        __builtin_amdgcn_s_barrier();
        __builtin_amdgcn_s_setprio(1);
#pragma unroll
        for (int i = 0; i < 3; ++i)
#pragma unroll
            for (int ni = 0; ni < 4; ++ni)
                acc[3 + i][ni] = __builtin_amdgcn_mfma_f32_16x16x32_bf16(
                    a[i], bbf[ni], acc[3 + i][ni], 0, 0, 0);
        __builtin_amdgcn_s_setprio(0);
        __builtin_amdgcn_s_barrier();
        __builtin_amdgcn_sched_barrier(0);

        // ================= phase 2 : kc1, mi 0..2 (+ B frags kc1) =================
#pragma unroll
        for (int ni = 0; ni < 4; ++ni) {
            const int r = wcN * 64 + ni * 16 + l15;
            bbf[ni] = *(const bf16x8*)(Bs + r * 128 + ((64 + lch * 16) ^ ((r & 7) << 4)));
        }
#pragma unroll
        for (int i = 0; i < 3; ++i) {
            const int r = wr * 96 + i * 16 + l15;
            a[i] = *(const bf16x8*)(As + r * 128 + ((64 + lch * 16) ^ ((r & 7) << 4)));
        }
        if (pf) { STAGE_B1(nb, step + 1, 1); STAGE_B1(nb, step + 1, 2); }
        __builtin_amdgcn_sched_barrier(0);
        __builtin_amdgcn_s_barrier();
        __builtin_amdgcn_s_setprio(1);
#pragma unroll
        for (int i = 0; i < 3; ++i)
#pragma unroll
            for (int ni = 0; ni < 4; ++ni)
                acc[i][ni] = __builtin_amdgcn_mfma_f32_16x16x32_bf16(
                    a[i], bbf[ni], acc[i][ni], 0, 0, 0);
        __builtin_amdgcn_s_setprio(0);
        __builtin_amdgcn_s_barrier();
        __builtin_amdgcn_sched_barrier(0);

        // ================= phase 3 : kc1, mi 3..5 =================
#pragma unroll
        for (int i = 0; i < 3; ++i) {
            const int r = wr * 96 + (3 + i) * 16 + l15;
            a[i] = *(const bf16x8*)(As + r * 128 + ((64 + lch * 16) ^ ((r & 7) << 4)));
        }
        if (pf) { STAGE_B1(nb, step + 1, 3); }
        __builtin_amdgcn_sched_barrier(0);
        __builtin_amdgcn_s_barrier();
        __builtin_amdgcn_s_setprio(1);
#pragma unroll
        for (int i = 0; i < 3; ++i)
#pragma unroll
            for (int ni = 0; ni < 4; ++ni)
                acc[3 + i][ni] = __builtin_amdgcn_mfma_f32_16x16x32_bf16(
                    a[i], bbf[ni], acc[3 + i][ni], 0, 0, 0);
        __builtin_amdgcn_s_setprio(0);
        __builtin_amdgcn_s_barrier();
        __builtin_amdgcn_sched_barrier(0);
    }

    // epilogue: D layout col = lane&15, row = (lane>>4)*4 + j
    float* ob = out + (size_t)b * OO * NSP + (size_t)(h0 + wcN) * WW;
#pragma unroll
    for (int mi = 0; mi < 6; ++mi)
#pragma unroll
        for (int ni = 0; ni < 4; ++ni)
#pragma unroll
            for (int j = 0; j < 4; ++j) {
                const int o = wr * 96 + mi * 16 + lch * 4 + j;
                const int w = ni * 16 + l15;
                ob[(size_t)o * NSP + w] = acc[mi][ni][j];
            }
}

extern "C" void kernel_launch(void* const* d_in, const int* in_sizes, int n_in,
                              void* d_out, int out_size, void* d_ws, size_t ws_size,
                              hipStream_t stream) {
    const float* x  = (const float*)d_in[0];
    const float* ew = (const float*)d_in[1];
    const float* rw = (const float*)d_in[2];
    const float* rb = (const float*)d_in[3];
    float* out = (float*)d_out;

    char* ws = (char*)d_ws;
    float*  pooled  = (float*)(ws + 0);                      // 24576 B
    __bf16* zp      = (__bf16*)(ws + 24576);                 // 1024 B
    __bf16* xT      = (__bf16*)(ws + 65536);                 // 50,331,648 B
    __bf16* wmT     = (__bf16*)(ws + 65536 + 50331648);      // 21,233,664 B

    hipMemsetAsync(ws, 0, 25600, stream);

    hipFuncSetAttribute((const void*)conv_kernel,
                        hipFuncAttributeMaxDynamicSharedMemorySize, 2 * BUFE * 2);

    hipLaunchKernelGGL(transpose_pool_kernel, dim3(HH, BB), dim3(256), 0, stream,
                       x, xT, pooled);
    hipLaunchKernelGGL(mix_kernel, dim3(OO, 8), dim3(256), 0, stream,
                       ew, pooled, rw, rb, wmT);
    hipLaunchKernelGGL(conv_kernel, dim3(512), dim3(512), 2 * BUFE * 2, stream,
                       xT, wmT, zp, out);
}

// Round 13
// 142.986 us; speedup vs baseline: 1.0613x; 1.0613x over previous
//
#include <hip/hip_runtime.h>
#include <hip/hip_bf16.h>

#define BB 32
#define CC 192
#define HH 64
#define WW 64
#define OO 192
#define EE 8
#define KTOT (CC*9)      // 1728
#define NSP (HH*WW)      // 4096
#define EWN (OO*CC*9)    // 331776 per expert

typedef __attribute__((ext_vector_type(8))) __bf16 bf16x8;
typedef __attribute__((ext_vector_type(4))) float f32x4;

// async global->LDS, 16B per lane (dest = wave-uniform base + lane*16)
__device__ __forceinline__ void gl_lds16(const void* g, void* l) {
    __builtin_amdgcn_global_load_lds(
        (const __attribute__((address_space(1))) unsigned int*)g,
        (__attribute__((address_space(3))) unsigned int*)l, 16, 0, 0);
}

// ---------------- kernel 1: fused transpose (NCHW f32 -> NHWC bf16) + global avg pool ----
__global__ __launch_bounds__(256) void transpose_pool_kernel(const float* __restrict__ x,
                                                             __bf16* __restrict__ xT,
                                                             float* __restrict__ pooled) {
    const int h = blockIdx.x, b = blockIdx.y;
    __shared__ float T[CC][65];   // 49920 B
    const int t = threadIdx.x;
    const float* xb = x + (size_t)b * CC * NSP + h * WW;
#pragma unroll
    for (int i = 0; i < 12; ++i) {
        const int g = i * 256 + t;          // 0..3071
        const int c = g >> 4;
        const int w4 = (g & 15) * 4;
        float4 v = *(const float4*)(xb + (size_t)c * NSP + w4);
        T[c][w4 + 0] = v.x; T[c][w4 + 1] = v.y;
        T[c][w4 + 2] = v.z; T[c][w4 + 3] = v.w;
    }
    __syncthreads();
    if (t < CC) {
        float s = 0.f;
#pragma unroll 8
        for (int w = 0; w < WW; ++w) s += T[t][w];
        atomicAdd(pooled + b * CC + t, s);
    }
#pragma unroll
    for (int i = 0; i < 6; ++i) {
        const int ch = i * 256 + t;         // 0..1535
        const int w = ch / 24;
        const int cg = ch - w * 24;
        bf16x8 o;
#pragma unroll
        for (int j = 0; j < 8; ++j) o[j] = (__bf16)T[cg * 8 + j][w];
        *(bf16x8*)(xT + (((size_t)b * HH + h) * WW + w) * CC + cg * 8) = o;
    }
}

// ---------------- kernel 2: mix expert weights -> bf16 (LDS-staged, coalesced reads) ----
// dest: wmT[b][o][(kh*3+kw)*192 + c]; src i = (o*192+c)*9 + (kh*3+kw)
// compute reads es at word-stride 9 -> gcd(9,32)=1 -> conflict-free.
__global__ __launch_bounds__(256) void mix_kernel(const float* __restrict__ ew,
                                                  const float* __restrict__ pooled,
                                                  const float* __restrict__ rw,
                                                  const float* __restrict__ rb,
                                                  __bf16* __restrict__ wmT) {
    __shared__ float r[4 * EE];
    __shared__ float es[EE * KTOT];   // 55296 B
    const int t = threadIdx.x;
    const int o = blockIdx.x;
    const int b0 = blockIdx.y * 4;
    const size_t base = (size_t)o * KTOT;
    for (int u = t; u < EE * (KTOT / 4); u += 256) {
        const int e = u / (KTOT / 4);
        const int s4 = u - e * (KTOT / 4);
        *(float4*)&es[e * KTOT + s4 * 4] =
            *(const float4*)(ew + (size_t)e * EWN + base + s4 * 4);
    }
    {
        const int p = t >> 3, q = t & 7;
        if (p < 32) {
            const int bl = p >> 3, e = p & 7;
            const float* pb = pooled + (b0 + bl) * CC + q * 24;
            const float* we = rw + e * CC + q * 24;
            float s = 0.f;
#pragma unroll
            for (int c = 0; c < 24; ++c) s += pb[c] * we[c];
            s += __shfl_xor(s, 4);
            s += __shfl_xor(s, 2);
            s += __shfl_xor(s, 1);
            if (q == 0) {
                s = s * (1.0f / 4096.0f) + rb[e];
                r[bl * EE + e] = 1.0f / (1.0f + expf(-s));
            }
        }
    }
    __syncthreads();
    for (int i = 0; i < 7; ++i) {
        const int jl = t + 256 * i;
        if (jl >= KTOT) break;
        const int c = jl % 192;
        const int t9 = jl / 192;
        const int s = c * 9 + t9;
        float w8[EE];
#pragma unroll
        for (int e = 0; e < EE; ++e) w8[e] = es[e * KTOT + s];
#pragma unroll
        for (int bi = 0; bi < 4; ++bi) {
            float acc = 0.f;
#pragma unroll
            for (int e = 0; e < EE; ++e) acc += r[bi * EE + e] * w8[e];
            wmT[(size_t)(b0 + bi) * EWN + base + jl] = (__bf16)acc;
        }
    }
}

// ---------------- kernel 3: NHWC implicit-GEMM conv (proven R3/R10 structure) ----------------
// 192(o) x 128(n = 2 h-rows x 64 w), BK=64, 512 thr (8 waves 4Mx2N).
// dbuf 2x40KB -> 2 blocks/CU; depth-1 prefetch, counted vmcnt(5); plain stores.
#define A_ELEMS (192*64)
#define B_ELEMS (128*64)
#define BUFE (A_ELEMS + B_ELEMS)   // 20480 bf16 = 40960 B

__global__ __launch_bounds__(512) void conv_kernel(const __bf16* __restrict__ xT,
                                                   const __bf16* __restrict__ wmT,
                                                   const __bf16* __restrict__ zp,
                                                   float* __restrict__ out) {
    extern __shared__ __bf16 smem[];   // 2 * BUFE = 81920 B

    // bijective XCD swizzle: 1024 blocks; each XCD gets 4 consecutive b x 32 h-pairs
    const int gid = blockIdx.x;              // 0..1023
    const int nid = (gid & 7) * 128 + (gid >> 3);
    const int b  = nid >> 5;                 // 0..31
    const int h0 = (nid & 31) * 2;           // 0,2,..,62

    const int t = threadIdx.x;
    const int lane = t & 63;
    const int wv = t >> 6;                   // 0..7
    const int wr = wv >> 1;                  // 0..3 (M quadrant: 48 rows)
    const int wc = wv & 1;                   // 0..1 (N half: one h-row)
    const int l15 = lane & 15, lch = lane >> 4;
    const int lrow = lane >> 3;              // 0..7
    const int offB = (((lane & 7) ^ lrow) << 4);   // pre-swizzled source byte offset

    const char* wmb = (const char*)(wmT + (size_t)b * (OO * KTOT));
    const char* xtb = (const char*)(xT + (size_t)b * (HH * WW * CC));
    const char* zpb = (const char*)zp;

    f32x4 acc[3][4];
#pragma unroll
    for (int mi = 0; mi < 3; ++mi)
#pragma unroll
        for (int ni = 0; ni < 4; ++ni) acc[mi][ni] = (f32x4){0.f, 0.f, 0.f, 0.f};

    auto STAGE = [&](int buf, int step) {
        const int t9 = step / 3;
        const int cc = step - t9 * 3;
        const int kh = t9 / 3;
        const int kw = t9 - kh * 3;
        const int c0 = cc * 64;
        __bf16* As = smem + buf * BUFE;
        __bf16* Bs = As + A_ELEMS;
        const size_t kB = (size_t)step * 128;
#pragma unroll
        for (int i = 0; i < 3; ++i) {
            const int chunk = wv * 3 + i;
            const char* src = wmb + (size_t)(chunk * 8 + lrow) * (KTOT * 2) + kB + offB;
            gl_lds16(src, (void*)(As + chunk * 512));
        }
#pragma unroll
        for (int i = 0; i < 2; ++i) {
            const int chunk = wv * 2 + i;
            const int n = chunk * 8 + lrow;          // 0..127
            const int hl = n >> 6;
            const int w = n & 63;
            const int hp = h0 + hl + kh - 1;
            const int wp = w + kw - 1;
            const bool ok = ((unsigned)hp < (unsigned)HH) && ((unsigned)wp < (unsigned)WW);
            const char* src = ok
                ? xtb + ((size_t)(hp * WW + wp) * CC + c0) * 2 + offB
                : zpb + offB;
            gl_lds16(src, (void*)(Bs + chunk * 512));
        }
    };

    STAGE(0, 0);                                          // 5 outstanding / wave
    for (int step = 0; step < 27; ++step) {
        const int cur = step & 1;
        if (step + 1 < 27) {
            STAGE(cur ^ 1, step + 1);                     // -> 10 outstanding
            asm volatile("s_waitcnt vmcnt(5)" ::: "memory");  // cur's 5 landed
        } else {
            asm volatile("s_waitcnt vmcnt(0)" ::: "memory");
        }
        __builtin_amdgcn_s_barrier();
        __builtin_amdgcn_sched_barrier(0);

        const __bf16* As = smem + cur * BUFE;
        const __bf16* Bs = As + A_ELEMS;
#pragma unroll
        for (int kc = 0; kc < 2; ++kc) {
            bf16x8 a[3], bbf[4];
#pragma unroll
            for (int mi = 0; mi < 3; ++mi) {
                const int r = wr * 48 + mi * 16 + l15;
                const int col = (kc * 64 + lch * 16) ^ ((r & 7) << 4);
                a[mi] = *(const bf16x8*)((const char*)As + r * 128 + col);
            }
#pragma unroll
            for (int ni = 0; ni < 4; ++ni) {
                const int r = wc * 64 + ni * 16 + l15;
                const int col = (kc * 64 + lch * 16) ^ ((r & 7) << 4);
                bbf[ni] = *(const bf16x8*)((const char*)Bs + r * 128 + col);
            }
            __builtin_amdgcn_s_setprio(1);
#pragma unroll
            for (int mi = 0; mi < 3; ++mi)
#pragma unroll
                for (int ni = 0; ni < 4; ++ni)
                    acc[mi][ni] = __builtin_amdgcn_mfma_f32_16x16x32_bf16(
                        a[mi], bbf[ni], acc[mi][ni], 0, 0, 0);
            __builtin_amdgcn_s_setprio(0);
        }
        __builtin_amdgcn_s_barrier();
        __builtin_amdgcn_sched_barrier(0);
    }

    // epilogue: D layout col = lane&15, row = (lane>>4)*4 + j
    float* ob = out + (size_t)b * OO * NSP + (size_t)(h0 + wc) * WW;
#pragma unroll
    for (int mi = 0; mi < 3; ++mi)
#pragma unroll
        for (int ni = 0; ni < 4; ++ni)
#pragma unroll
            for (int j = 0; j < 4; ++j) {
                const int o = wr * 48 + mi * 16 + lch * 4 + j;
                const int w = ni * 16 + l15;
                ob[(size_t)o * NSP + w] = acc[mi][ni][j];
            }
}

extern "C" void kernel_launch(void* const* d_in, const int* in_sizes, int n_in,
                              void* d_out, int out_size, void* d_ws, size_t ws_size,
                              hipStream_t stream) {
    const float* x  = (const float*)d_in[0];
    const float* ew = (const float*)d_in[1];
    const float* rw = (const float*)d_in[2];
    const float* rb = (const float*)d_in[3];
    float* out = (float*)d_out;

    char* ws = (char*)d_ws;
    float*  pooled  = (float*)(ws + 0);                      // 24576 B
    __bf16* zp      = (__bf16*)(ws + 24576);                 // 1024 B
    __bf16* xT      = (__bf16*)(ws + 65536);                 // 50,331,648 B
    __bf16* wmT     = (__bf16*)(ws + 65536 + 50331648);      // 21,233,664 B

    // one memset covers pooled + zero page
    hipMemsetAsync(ws, 0, 25600, stream);

    hipFuncSetAttribute((const void*)conv_kernel,
                        hipFuncAttributeMaxDynamicSharedMemorySize, 2 * BUFE * 2);

    hipLaunchKernelGGL(transpose_pool_kernel, dim3(HH, BB), dim3(256), 0, stream,
                       x, xT, pooled);
    hipLaunchKernelGGL(mix_kernel, dim3(OO, 8), dim3(256), 0, stream,
                       ew, pooled, rw, rb, wmT);
    hipLaunchKernelGGL(conv_kernel, dim3(1024), dim3(512), 2 * BUFE * 2, stream,
                       xT, wmT, zp, out);
}

// Round 14
// 138.195 us; speedup vs baseline: 1.0981x; 1.0347x over previous
//
#include <hip/hip_runtime.h>
#include <hip/hip_bf16.h>

#define BB 32
#define CC 192
#define HH 64
#define WW 64
#define OO 192
#define EE 8
#define KTOT (CC*9)      // 1728
#define NSP (HH*WW)      // 4096
#define EWN (OO*CC*9)    // 331776 per expert

typedef __attribute__((ext_vector_type(8))) __bf16 bf16x8;
typedef __attribute__((ext_vector_type(4))) float f32x4;

// async global->LDS, 16B per lane (dest = wave-uniform base + lane*16)
__device__ __forceinline__ void gl_lds16(const void* g, void* l) {
    __builtin_amdgcn_global_load_lds(
        (const __attribute__((address_space(1))) unsigned int*)g,
        (__attribute__((address_space(3))) unsigned int*)l, 16, 0, 0);
}

// ---------------- kernel 1: fused transpose (NCHW f32 -> NHWC bf16) + global avg pool ----
__global__ __launch_bounds__(256) void transpose_pool_kernel(const float* __restrict__ x,
                                                             __bf16* __restrict__ xT,
                                                             float* __restrict__ pooled) {
    const int h = blockIdx.x, b = blockIdx.y;
    __shared__ float T[CC][65];   // 49920 B
    const int t = threadIdx.x;
    const float* xb = x + (size_t)b * CC * NSP + h * WW;
#pragma unroll
    for (int i = 0; i < 12; ++i) {
        const int g = i * 256 + t;          // 0..3071
        const int c = g >> 4;
        const int w4 = (g & 15) * 4;
        float4 v = *(const float4*)(xb + (size_t)c * NSP + w4);
        T[c][w4 + 0] = v.x; T[c][w4 + 1] = v.y;
        T[c][w4 + 2] = v.z; T[c][w4 + 3] = v.w;
    }
    __syncthreads();
    if (t < CC) {
        float s = 0.f;
#pragma unroll 8
        for (int w = 0; w < WW; ++w) s += T[t][w];
        atomicAdd(pooled + b * CC + t, s);
    }
#pragma unroll
    for (int i = 0; i < 6; ++i) {
        const int ch = i * 256 + t;         // 0..1535
        const int w = ch / 24;
        const int cg = ch - w * 24;
        bf16x8 o;
#pragma unroll
        for (int j = 0; j < 8; ++j) o[j] = (__bf16)T[cg * 8 + j][w];
        *(bf16x8*)(xT + (((size_t)b * HH + h) * WW + w) * CC + cg * 8) = o;
    }
}

// ---------------- kernel 2: mix expert weights -> bf16 (LDS-staged, coalesced reads) ----
// dest: wmT[b][o][(kh*3+kw)*192 + c]; src i = (o*192+c)*9 + (kh*3+kw)
// compute reads es at word-stride 9 -> gcd(9,32)=1 -> conflict-free.
__global__ __launch_bounds__(256) void mix_kernel(const float* __restrict__ ew,
                                                  const float* __restrict__ pooled,
                                                  const float* __restrict__ rw,
                                                  const float* __restrict__ rb,
                                                  __bf16* __restrict__ wmT) {
    __shared__ float r[4 * EE];
    __shared__ float es[EE * KTOT];   // 55296 B
    const int t = threadIdx.x;
    const int o = blockIdx.x;
    const int b0 = blockIdx.y * 4;
    const size_t base = (size_t)o * KTOT;
    for (int u = t; u < EE * (KTOT / 4); u += 256) {
        const int e = u / (KTOT / 4);
        const int s4 = u - e * (KTOT / 4);
        *(float4*)&es[e * KTOT + s4 * 4] =
            *(const float4*)(ew + (size_t)e * EWN + base + s4 * 4);
    }
    {
        const int p = t >> 3, q = t & 7;
        if (p < 32) {
            const int bl = p >> 3, e = p & 7;
            const float* pb = pooled + (b0 + bl) * CC + q * 24;
            const float* we = rw + e * CC + q * 24;
            float s = 0.f;
#pragma unroll
            for (int c = 0; c < 24; ++c) s += pb[c] * we[c];
            s += __shfl_xor(s, 4);
            s += __shfl_xor(s, 2);
            s += __shfl_xor(s, 1);
            if (q == 0) {
                s = s * (1.0f / 4096.0f) + rb[e];
                r[bl * EE + e] = 1.0f / (1.0f + expf(-s));
            }
        }
    }
    __syncthreads();
    for (int i = 0; i < 7; ++i) {
        const int jl = t + 256 * i;
        if (jl >= KTOT) break;
        const int c = jl % 192;
        const int t9 = jl / 192;
        const int s = c * 9 + t9;
        float w8[EE];
#pragma unroll
        for (int e = 0; e < EE; ++e) w8[e] = es[e * KTOT + s];
#pragma unroll
        for (int bi = 0; bi < 4; ++bi) {
            float acc = 0.f;
#pragma unroll
            for (int e = 0; e < EE; ++e) acc += r[bi * EE + e] * w8[e];
            wmT[(size_t)(b0 + bi) * EWN + base + jl] = (__bf16)acc;
        }
    }
}

// ---------------- kernel 3: NHWC implicit-GEMM conv (proven R3/R10 structure) ----------------
// 192(o) x 128(n = 2 h-rows x 64 w), BK=64, 512 thr (8 waves 4Mx2N).
// dbuf 2x40KB -> 2 blocks/CU; depth-1 prefetch, counted vmcnt(5).
// Nontemporal epilogue stores: keeps out (98 MB) out of L2/L3 so x+xT+wmT
// (171 MB) stay L3-resident across graph replays (269 MB would overflow 256 MB).
#define A_ELEMS (192*64)
#define B_ELEMS (128*64)
#define BUFE (A_ELEMS + B_ELEMS)   // 20480 bf16 = 40960 B

__global__ __launch_bounds__(512) void conv_kernel(const __bf16* __restrict__ xT,
                                                   const __bf16* __restrict__ wmT,
                                                   const __bf16* __restrict__ zp,
                                                   float* __restrict__ out) {
    extern __shared__ __bf16 smem[];   // 2 * BUFE = 81920 B

    // bijective XCD swizzle: 1024 blocks; each XCD gets 4 consecutive b x 32 h-pairs
    const int gid = blockIdx.x;              // 0..1023
    const int nid = (gid & 7) * 128 + (gid >> 3);
    const int b  = nid >> 5;                 // 0..31
    const int h0 = (nid & 31) * 2;           // 0,2,..,62

    const int t = threadIdx.x;
    const int lane = t & 63;
    const int wv = t >> 6;                   // 0..7
    const int wr = wv >> 1;                  // 0..3 (M quadrant: 48 rows)
    const int wc = wv & 1;                   // 0..1 (N half: one h-row)
    const int l15 = lane & 15, lch = lane >> 4;
    const int lrow = lane >> 3;              // 0..7
    const int offB = (((lane & 7) ^ lrow) << 4);   // pre-swizzled source byte offset

    const char* wmb = (const char*)(wmT + (size_t)b * (OO * KTOT));
    const char* xtb = (const char*)(xT + (size_t)b * (HH * WW * CC));
    const char* zpb = (const char*)zp;

    f32x4 acc[3][4];
#pragma unroll
    for (int mi = 0; mi < 3; ++mi)
#pragma unroll
        for (int ni = 0; ni < 4; ++ni) acc[mi][ni] = (f32x4){0.f, 0.f, 0.f, 0.f};

    auto STAGE = [&](int buf, int step) {
        const int t9 = step / 3;
        const int cc = step - t9 * 3;
        const int kh = t9 / 3;
        const int kw = t9 - kh * 3;
        const int c0 = cc * 64;
        __bf16* As = smem + buf * BUFE;
        __bf16* Bs = As + A_ELEMS;
        const size_t kB = (size_t)step * 128;
#pragma unroll
        for (int i = 0; i < 3; ++i) {
            const int chunk = wv * 3 + i;
            const char* src = wmb + (size_t)(chunk * 8 + lrow) * (KTOT * 2) + kB + offB;
            gl_lds16(src, (void*)(As + chunk * 512));
        }
#pragma unroll
        for (int i = 0; i < 2; ++i) {
            const int chunk = wv * 2 + i;
            const int n = chunk * 8 + lrow;          // 0..127
            const int hl = n >> 6;
            const int w = n & 63;
            const int hp = h0 + hl + kh - 1;
            const int wp = w + kw - 1;
            const bool ok = ((unsigned)hp < (unsigned)HH) && ((unsigned)wp < (unsigned)WW);
            const char* src = ok
                ? xtb + ((size_t)(hp * WW + wp) * CC + c0) * 2 + offB
                : zpb + offB;
            gl_lds16(src, (void*)(Bs + chunk * 512));
        }
    };

    STAGE(0, 0);                                          // 5 outstanding / wave
    for (int step = 0; step < 27; ++step) {
        const int cur = step & 1;
        if (step + 1 < 27) {
            STAGE(cur ^ 1, step + 1);                     // -> 10 outstanding
            asm volatile("s_waitcnt vmcnt(5)" ::: "memory");  // cur's 5 landed
        } else {
            asm volatile("s_waitcnt vmcnt(0)" ::: "memory");
        }
        __builtin_amdgcn_s_barrier();
        __builtin_amdgcn_sched_barrier(0);

        const __bf16* As = smem + cur * BUFE;
        const __bf16* Bs = As + A_ELEMS;
#pragma unroll
        for (int kc = 0; kc < 2; ++kc) {
            bf16x8 a[3], bbf[4];
#pragma unroll
            for (int mi = 0; mi < 3; ++mi) {
                const int r = wr * 48 + mi * 16 + l15;
                const int col = (kc * 64 + lch * 16) ^ ((r & 7) << 4);
                a[mi] = *(const bf16x8*)((const char*)As + r * 128 + col);
            }
#pragma unroll
            for (int ni = 0; ni < 4; ++ni) {
                const int r = wc * 64 + ni * 16 + l15;
                const int col = (kc * 64 + lch * 16) ^ ((r & 7) << 4);
                bbf[ni] = *(const bf16x8*)((const char*)Bs + r * 128 + col);
            }
            __builtin_amdgcn_s_setprio(1);
#pragma unroll
            for (int mi = 0; mi < 3; ++mi)
#pragma unroll
                for (int ni = 0; ni < 4; ++ni)
                    acc[mi][ni] = __builtin_amdgcn_mfma_f32_16x16x32_bf16(
                        a[mi], bbf[ni], acc[mi][ni], 0, 0, 0);
            __builtin_amdgcn_s_setprio(0);
        }
        __builtin_amdgcn_s_barrier();
        __builtin_amdgcn_sched_barrier(0);
    }

    // epilogue: D layout col = lane&15, row = (lane>>4)*4 + j ; nontemporal stores
    float* ob = out + (size_t)b * OO * NSP + (size_t)(h0 + wc) * WW;
#pragma unroll
    for (int mi = 0; mi < 3; ++mi)
#pragma unroll
        for (int ni = 0; ni < 4; ++ni)
#pragma unroll
            for (int j = 0; j < 4; ++j) {
                const int o = wr * 48 + mi * 16 + lch * 4 + j;
                const int w = ni * 16 + l15;
                __builtin_nontemporal_store(acc[mi][ni][j], &ob[(size_t)o * NSP + w]);
            }
}

extern "C" void kernel_launch(void* const* d_in, const int* in_sizes, int n_in,
                              void* d_out, int out_size, void* d_ws, size_t ws_size,
                              hipStream_t stream) {
    const float* x  = (const float*)d_in[0];
    const float* ew = (const float*)d_in[1];
    const float* rw = (const float*)d_in[2];
    const float* rb = (const float*)d_in[3];
    float* out = (float*)d_out;

    char* ws = (char*)d_ws;
    float*  pooled  = (float*)(ws + 0);                      // 24576 B
    __bf16* zp      = (__bf16*)(ws + 24576);                 // 1024 B
    __bf16* xT      = (__bf16*)(ws + 65536);                 // 50,331,648 B
    __bf16* wmT     = (__bf16*)(ws + 65536 + 50331648);      // 21,233,664 B

    // one memset covers pooled + zero page
    hipMemsetAsync(ws, 0, 25600, stream);

    hipFuncSetAttribute((const void*)conv_kernel,
                        hipFuncAttributeMaxDynamicSharedMemorySize, 2 * BUFE * 2);

    hipLaunchKernelGGL(transpose_pool_kernel, dim3(HH, BB), dim3(256), 0, stream,
                       x, xT, pooled);
    hipLaunchKernelGGL(mix_kernel, dim3(OO, 8), dim3(256), 0, stream,
                       ew, pooled, rw, rb, wmT);
    hipLaunchKernelGGL(conv_kernel, dim3(1024), dim3(512), 2 * BUFE * 2, stream,
                       xT, wmT, zp, out);
}